// Round 10
// baseline (145.575 us; speedup 1.0000x reference)
//
#include <hip/hip_runtime.h>
#include <hip/hip_bf16.h>
#include <cstdint>

#define BATCH 4096
#define DIN   512
#define DH    256
#define DG    128
#define NH    8
#define NTOT  3328
#define RPB   2          // attn rows per block (R6/R9 showed 8 rows kills occupancy; 2 @ ~20KB keeps it)
#define SH    264        // h-row stride in shorts (528B rows -> 2-way banks, free)
#define RREG  (9 * SH)   // per-row z1 region: 8 heads + ones row; first 2048 shorts reused for z1cb

typedef __bf16 bf16x8 __attribute__((ext_vector_type(8)));
typedef float  f32x4  __attribute__((ext_vector_type(4)));

__device__ __forceinline__ unsigned short f2bf(float f) {
    union { float f; uint32_t u; } v; v.f = f;
    uint32_t u = v.u;
    u += 0x7fffu + ((u >> 16) & 1u);
    return (unsigned short)(u >> 16);
}
__device__ __forceinline__ float bf2f(unsigned short s) {
    union { uint32_t u; float f; } v; v.u = ((uint32_t)s) << 16;
    return v.f;
}

__device__ __forceinline__ void async16(const unsigned short* g, unsigned short* l) {
    __builtin_amdgcn_global_load_lds(
        (const __attribute__((address_space(1))) unsigned int*)(uintptr_t)g,
        (__attribute__((address_space(3))) unsigned int*)(uintptr_t)l,
        16, 0, 0);
}

// ---------------- merged prep: cvt_x + transpose/concat weights (R5-proven) ----------------
__global__ __launch_bounds__(256) void prep_kernel(const float* __restrict__ x,
                                                   const float* __restrict__ Wh,
                                                   const float* __restrict__ Wz1,
                                                   const float* __restrict__ Wz2,
                                                   unsigned short* __restrict__ xb,
                                                   unsigned short* __restrict__ Wt) {
    __shared__ float tile[32][33];
    int bid = blockIdx.x;
    int t = threadIdx.x;
    if (bid < 2048) {
        int i = (bid * 256 + t) * 4;
        float4 v = *(const float4*)(x + i);
        ushort4 o;
        o.x = f2bf(v.x); o.y = f2bf(v.y); o.z = f2bf(v.z); o.w = f2bf(v.w);
        *(ushort4*)(xb + i) = o;
        return;
    }
    int b2 = bid - 2048;
    int n0 = (b2 % 104) * 32;
    int k0 = (b2 / 104) * 32;
    const float* W; int ldn, nl;
    if (n0 < 256)       { W = Wh;  ldn = 256;  nl = n0; }
    else if (n0 < 2304) { W = Wz1; ldn = 2048; nl = n0 - 256; }
    else                { W = Wz2; ldn = 1024; nl = n0 - 2304; }
    int tx = t & 31, ty = t >> 5;
    #pragma unroll
    for (int i = 0; i < 4; i++) {
        int kk = ty + i * 8;
        tile[kk][tx] = W[(size_t)(k0 + kk) * ldn + nl + tx];
    }
    __syncthreads();
    #pragma unroll
    for (int i = 0; i < 4; i++) {
        int nn = ty + i * 8;
        Wt[(size_t)(n0 + nn) * 512 + k0 + tx] = f2bf(tile[tx][nn]);
    }
}

// ------------- fused GEMM: Zb[4096][3328](bf16) = xb @ Wt^T (R7-proven) -------------
__global__ __launch_bounds__(256) void gemm_kernel(const unsigned short* __restrict__ xb,
                                                   const unsigned short* __restrict__ Wt,
                                                   unsigned short* __restrict__ Zb) {
    __shared__ unsigned short As[128 * 64];
    __shared__ unsigned short Bs[128 * 64];
    const int m0 = blockIdx.y * 128;
    const int n0 = blockIdx.x * 128;
    const int t = threadIdx.x;
    const int w = t >> 6, lane = t & 63;
    const int wm = (w >> 1) * 64, wn = (w & 1) * 64;
    const int lrow = lane & 15, q = lane >> 4;

    f32x4 acc[4][4] = {};

    for (int k0 = 0; k0 < DIN; k0 += 64) {
        __syncthreads();
        #pragma unroll
        for (int j = 0; j < 4; j++) {
            int gidx = (w * 4 + j) * 64 + lane;
            int row = gidx >> 3, slot = gidx & 7;
            int src = slot ^ (row & 7);
            const unsigned short* ga = xb + (size_t)(m0 + row) * DIN + k0 + src * 8;
            const unsigned short* gb = Wt + (size_t)(n0 + row) * DIN + k0 + src * 8;
            async16(ga, As + (w * 4 + j) * 512);
            async16(gb, Bs + (w * 4 + j) * 512);
        }
        __syncthreads();
        #pragma unroll
        for (int ks = 0; ks < 2; ks++) {
            bf16x8 af[4], bfr[4];
            #pragma unroll
            for (int i = 0; i < 4; i++) {
                int row = wm + i * 16 + lrow;
                int phys = (ks * 4 + q) ^ (row & 7);
                af[i] = *reinterpret_cast<const bf16x8*>(As + row * 64 + phys * 8);
            }
            #pragma unroll
            for (int j = 0; j < 4; j++) {
                int row = wn + j * 16 + lrow;
                int phys = (ks * 4 + q) ^ (row & 7);
                bfr[j] = *reinterpret_cast<const bf16x8*>(Bs + row * 64 + phys * 8);
            }
            #pragma unroll
            for (int i = 0; i < 4; i++)
                #pragma unroll
                for (int j = 0; j < 4; j++)
                    acc[i][j] = __builtin_amdgcn_mfma_f32_16x16x32_bf16(af[i], bfr[j], acc[i][j], 0, 0, 0);
        }
    }
    #pragma unroll
    for (int i = 0; i < 4; i++)
        #pragma unroll
        for (int j = 0; j < 4; j++) {
            int col = n0 + wn + j * 16 + lrow;
            int rbase = m0 + wm + i * 16 + q * 4;
            #pragma unroll
            for (int r = 0; r < 4; r++)
                Zb[(size_t)(rbase + r) * NTOT + col] = f2bf(acc[i][j][r]);
        }
}

// ------- 2-row attn block: LN ; Gram-MFMA ; in-place fragments ; MFMA tanh ; y -------
// R7 per-row algorithm; 2 rows amortize phases (4 barriers / 2 rows) at ~20KB LDS.
__global__ __launch_bounds__(256, 8) void attn_kernel(const unsigned short* __restrict__ Zb,
                                                      const float* __restrict__ bh,
                                                      const float* __restrict__ lns,
                                                      const float* __restrict__ lnb,
                                                      float* __restrict__ h_out,
                                                      float* __restrict__ y_out) {
    __shared__ __align__(16) unsigned short z1a[RPB * RREG + 7 * SH];  // 13.2 KB (+Gram row-overrun pad)
    __shared__ __align__(16) unsigned short z2b[RPB * 1024];           // 4 KB; raw [h][g] -> in-place z2A [g][h]
    __shared__ __align__(16) float hsr[RPB][DH];                       // 2 KB
    __shared__ float GLr[RPB][9][9];
    __shared__ float redH[RPB];
    __shared__ __align__(16) unsigned short zpad[8];
    const int b0 = blockIdx.x * RPB;
    const int t = threadIdx.x;
    const int wv = t >> 6, lane = t & 63;
    const int lrow = lane & 15, q = lane >> 4;

    // ---- stage: z1 (1 uint4/thread/row), z2 (1 uint4/thread), ones, zpad ----
    #pragma unroll
    for (int r = 0; r < RPB; r++) {
        uint4 v = *(const uint4*)(Zb + (size_t)(b0 + r) * NTOT + 256 + t * 8);
        *(uint4*)(z1a + r * RREG + (t >> 5) * SH + (t & 31) * 8) = v;
        z1a[r * RREG + 8 * SH + t] = 0x3F80;   // bf16 1.0 ones row
    }
    {
        int r = t >> 7, c = t & 127;
        uint4 v = *(const uint4*)(Zb + (size_t)(b0 + r) * NTOT + 2304 + c * 8);
        *(uint4*)(z2b + r * 1024 + c * 8) = v;
    }
    if (t < 8) zpad[t] = 0;

    // ---- LN: wave wv<2 -> row wv, 4 elems/lane, full-wave shuffle (no barrier) ----
    if (wv < 2) {
        int r = wv, d0 = lane * 4;
        const unsigned short* Zr = Zb + (size_t)(b0 + r) * NTOT;
        ushort4 hu = *(const ushort4*)(Zr + d0);
        float4 bv = *(const float4*)(bh + d0);
        float vv[4];
        vv[0] = fmaxf(bf2f(hu.x) + bv.x, 0.f);
        vv[1] = fmaxf(bf2f(hu.y) + bv.y, 0.f);
        vv[2] = fmaxf(bf2f(hu.z) + bv.z, 0.f);
        vv[3] = fmaxf(bf2f(hu.w) + bv.w, 0.f);
        float s = vv[0] + vv[1] + vv[2] + vv[3];
        float sq = vv[0] * vv[0] + vv[1] * vv[1] + vv[2] * vv[2] + vv[3] * vv[3];
        #pragma unroll
        for (int m = 32; m >= 1; m >>= 1) {
            s  += __shfl_xor(s,  m, 64);
            sq += __shfl_xor(sq, m, 64);
        }
        float mu  = s * (1.0f / 256.0f);
        float var = sq * (1.0f / 256.0f) - mu * mu;
        float rs = rsqrtf(var + 1e-6f);
        float4 lv = *(const float4*)(lns + d0);
        float4 ov = *(const float4*)(lnb + d0);
        float hv0 = (vv[0] - mu) * rs * lv.x + ov.x;
        float hv1 = (vv[1] - mu) * rs * lv.y + ov.y;
        float hv2 = (vv[2] - mu) * rs * lv.z + ov.z;
        float hv3 = (vv[3] - mu) * rs * lv.w + ov.w;
        *(float4*)(&hsr[r][d0]) = float4{hv0, hv1, hv2, hv3};
        *(float4*)(h_out + (size_t)(b0 + r) * DH + d0) = float4{hv0, hv1, hv2, hv3};
        float hp = hv0 + hv1 + hv2 + hv3;
        #pragma unroll
        for (int m = 32; m >= 1; m >>= 1) hp += __shfl_xor(hp, m, 64);
        if (lane == 0) redH[r] = hp;
    }
    __syncthreads();   // (#1) staging + LN results visible

    // ---- Gram via MFMA: wave wv<2 -> row wv ----
    if (wv < 2) {
        int r = wv;
        f32x4 g = {};
        #pragma unroll
        for (int ks = 0; ks < 8; ks++) {
            bf16x8 fr = *reinterpret_cast<const bf16x8*>(z1a + r * RREG + lrow * SH + ks * 32 + q * 8);
            g = __builtin_amdgcn_mfma_f32_16x16x32_bf16(fr, fr, g, 0, 0, 0);
        }
        #pragma unroll
        for (int i = 0; i < 4; i++) {
            int crow = q * 4 + i;
            if (crow < 9 && lrow < 9) GLr[r][crow][lrow] = g[i];
        }
    }
    // ---- stats raw-z2 reads -> regs (before in-place overwrite; barrier-ordered) ----
    const int sr = t >> 7, sg = t & 127;
    float z2g[NH];
    #pragma unroll
    for (int h = 0; h < NH; h++) z2g[h] = bf2f(z2b[sr * 1024 + h * 128 + sg]);
    __syncthreads();   // (#2) GLr visible; raw-z2 reads done

    // ---- repack reads (centered z1 -> regs): 2 d-values/thread ----
    uint32_t pr[2][4];
    {
        float mh[NH];
        #pragma unroll
        for (int h = 0; h < NH; h++) mh[h] = GLr[sr][h][8] * (1.0f / 256.0f);
        #pragma unroll
        for (int it = 0; it < 2; it++) {
            int d = (t & 127) + it * 128;
            #pragma unroll
            for (int h2 = 0; h2 < 4; h2++) {
                float c0 = bf2f(z1a[sr * RREG + (2 * h2) * SH + d])     - mh[2 * h2];
                float c1 = bf2f(z1a[sr * RREG + (2 * h2 + 1) * SH + d]) - mh[2 * h2 + 1];
                pr[it][h2] = (uint32_t)f2bf(c0) | ((uint32_t)f2bf(c1) << 16);
            }
        }
    }
    // ---- stats compute -> z2A regs ----
    uint32_t ps[4];
    {
        float mug = 0.f, qg = 0.f;
        #pragma unroll
        for (int h = 0; h < NH; h++) {
            mug += z2g[h] * GLr[sr][h][8];
            float inn = 0.f;
            #pragma unroll
            for (int h2 = 0; h2 < NH; h2++) inn += z2g[h2] * GLr[sr][h][h2];
            qg += z2g[h] * inn;
        }
        mug *= (1.0f / 256.0f);
        qg  *= (1.0f / 256.0f);
        float vg = fmaxf(qg - mug * mug, 0.0f);
        float A = 2.0f * 1.4426950408889634f / (sqrtf(vg) + 1e-6f);
        #pragma unroll
        for (int h2 = 0; h2 < 4; h2++)
            ps[h2] = (uint32_t)f2bf(z2g[2 * h2] * A) | ((uint32_t)f2bf(z2g[2 * h2 + 1] * A) << 16);
    }
    __syncthreads();   // (#3) all raw reads done

    // ---- in-place writes: z1cb [d][h] into z1a; z2A [g][h] into z2b ----
    #pragma unroll
    for (int it = 0; it < 2; it++) {
        int d = (t & 127) + it * 128;
        *(uint4*)(z1a + sr * RREG + d * 8) = uint4{pr[it][0], pr[it][1], pr[it][2], pr[it][3]};
    }
    *(uint4*)(z2b + sr * 1024 + sg * 8) = uint4{ps[0], ps[1], ps[2], ps[3]};
    __syncthreads();   // (#4) fragments ready

    // ---- main: wave wv -> row = wv>>1, g-tiles (wv&1)*4 .. +3 ----
    const int row = wv >> 1, gtb = (wv & 1) * 4;
    const unsigned short* bp = (q == 0) ? (z1a + row * RREG + lrow * 8) : zpad;
    const int binc = (q == 0) ? 128 : 0;
    bf16x8 af[4];
    #pragma unroll
    for (int gt = 0; gt < 4; gt++) {
        const unsigned short* pa = (q == 0) ? (z2b + row * 1024 + ((gtb + gt) * 16 + lrow) * 8) : zpad;
        af[gt] = *reinterpret_cast<const bf16x8*>(pa);
    }
    f32x4 czero = {};
    float yn[4][4] = {};
    #pragma unroll 4
    for (int dt = 0; dt < 16; dt++) {
        bf16x8 bfr = *reinterpret_cast<const bf16x8*>(bp + dt * binc);
        float hv = hsr[row][dt * 16 + lrow];
        #pragma unroll
        for (int gt = 0; gt < 4; gt++) {
            f32x4 c = __builtin_amdgcn_mfma_f32_16x16x32_bf16(af[gt], bfr, czero, 0, 0, 0);
            #pragma unroll
            for (int r4 = 0; r4 < 4; r4++) {
                float e = __builtin_amdgcn_exp2f(c[r4]);
                yn[gt][r4] = fmaf(hv, __builtin_amdgcn_rcpf(e + 1.0f), yn[gt][r4]);
            }
        }
    }
    #pragma unroll
    for (int m = 1; m <= 8; m <<= 1)
        #pragma unroll
        for (int gt = 0; gt < 4; gt++)
            #pragma unroll
            for (int r4 = 0; r4 < 4; r4++)
                yn[gt][r4] += __shfl_xor(yn[gt][r4], m, 64);
    if (lrow == 0) {
        float Hs = redH[row];
        #pragma unroll
        for (int gt = 0; gt < 4; gt++)
            #pragma unroll
            for (int r4 = 0; r4 < 4; r4++)
                y_out[(size_t)(b0 + row) * DG + (gtb + gt) * 16 + q * 4 + r4] = Hs - 2.0f * yn[gt][r4];
    }
}

extern "C" void kernel_launch(void* const* d_in, const int* in_sizes, int n_in,
                              void* d_out, int out_size, void* d_ws, size_t ws_size,
                              hipStream_t stream) {
    const float* x   = (const float*)d_in[0];
    const float* Wh  = (const float*)d_in[1];
    const float* bh  = (const float*)d_in[2];
    const float* Wz1 = (const float*)d_in[3];
    const float* Wz2 = (const float*)d_in[4];
    const float* lns = (const float*)d_in[5];
    const float* lnb = (const float*)d_in[6];
    float* h_out = (float*)d_out;
    float* y_out = h_out + (size_t)BATCH * DH;

    char* ws = (char*)d_ws;
    unsigned short* Zb = (unsigned short*)ws;               // 27,262,976 B
    unsigned short* xb = (unsigned short*)(ws + 27262976);  //  4,194,304 B
    unsigned short* Wt = (unsigned short*)(ws + 31457280);  //  3,407,872 B (~34.9 MB)

    prep_kernel<<<3712, 256, 0, stream>>>(x, Wh, Wz1, Wz2, xb, Wt);
    gemm_kernel<<<dim3(NTOT / 128, BATCH / 128), 256, 0, stream>>>(xb, Wt, Zb);
    attn_kernel<<<BATCH / RPB, 256, 0, stream>>>(Zb, bh, lns, lnb, h_out, y_out);
}

// Round 11
// 141.596 us; speedup vs baseline: 1.0281x; 1.0281x over previous
//
#include <hip/hip_runtime.h>
#include <hip/hip_bf16.h>
#include <cstdint>

#define BATCH 4096
#define DIN   512
#define DH    256
#define DG    128
#define NH    8
#define NTOT  3328
#define RPB   2          // rows per attn block
#define SH    264        // raw-z1 row stride in shorts (528B rows -> 2-way banks, free)
#define RREG  (9 * SH)   // per-row raw z1 region: 8 heads + ones row

typedef __bf16 bf16x8 __attribute__((ext_vector_type(8)));
typedef float  f32x4  __attribute__((ext_vector_type(4)));

__device__ __forceinline__ unsigned short f2bf(float f) {
    union { float f; uint32_t u; } v; v.f = f;
    uint32_t u = v.u;
    u += 0x7fffu + ((u >> 16) & 1u);
    return (unsigned short)(u >> 16);
}
__device__ __forceinline__ float bf2f(unsigned short s) {
    union { uint32_t u; float f; } v; v.u = ((uint32_t)s) << 16;
    return v.f;
}

__device__ __forceinline__ void async16(const unsigned short* g, unsigned short* l) {
    __builtin_amdgcn_global_load_lds(
        (const __attribute__((address_space(1))) unsigned int*)(uintptr_t)g,
        (__attribute__((address_space(3))) unsigned int*)(uintptr_t)l,
        16, 0, 0);
}

// ---------------- merged prep: cvt_x + transpose/concat weights (R5-proven) ----------------
__global__ __launch_bounds__(256) void prep_kernel(const float* __restrict__ x,
                                                   const float* __restrict__ Wh,
                                                   const float* __restrict__ Wz1,
                                                   const float* __restrict__ Wz2,
                                                   unsigned short* __restrict__ xb,
                                                   unsigned short* __restrict__ Wt) {
    __shared__ float tile[32][33];
    int bid = blockIdx.x;
    int t = threadIdx.x;
    if (bid < 2048) {
        int i = (bid * 256 + t) * 4;
        float4 v = *(const float4*)(x + i);
        ushort4 o;
        o.x = f2bf(v.x); o.y = f2bf(v.y); o.z = f2bf(v.z); o.w = f2bf(v.w);
        *(ushort4*)(xb + i) = o;
        return;
    }
    int b2 = bid - 2048;
    int n0 = (b2 % 104) * 32;
    int k0 = (b2 / 104) * 32;
    const float* W; int ldn, nl;
    if (n0 < 256)       { W = Wh;  ldn = 256;  nl = n0; }
    else if (n0 < 2304) { W = Wz1; ldn = 2048; nl = n0 - 256; }
    else                { W = Wz2; ldn = 1024; nl = n0 - 2304; }
    int tx = t & 31, ty = t >> 5;
    #pragma unroll
    for (int i = 0; i < 4; i++) {
        int kk = ty + i * 8;
        tile[kk][tx] = W[(size_t)(k0 + kk) * ldn + nl + tx];
    }
    __syncthreads();
    #pragma unroll
    for (int i = 0; i < 4; i++) {
        int nn = ty + i * 8;
        Wt[(size_t)(n0 + nn) * 512 + k0 + tx] = f2bf(tile[tx][nn]);
    }
}

// ------------- fused GEMM: Zb[4096][3328](bf16) = xb @ Wt^T (R7-proven) -------------
__global__ __launch_bounds__(256) void gemm_kernel(const unsigned short* __restrict__ xb,
                                                   const unsigned short* __restrict__ Wt,
                                                   unsigned short* __restrict__ Zb) {
    __shared__ unsigned short As[128 * 64];
    __shared__ unsigned short Bs[128 * 64];
    const int m0 = blockIdx.y * 128;
    const int n0 = blockIdx.x * 128;
    const int t = threadIdx.x;
    const int w = t >> 6, lane = t & 63;
    const int wm = (w >> 1) * 64, wn = (w & 1) * 64;
    const int lrow = lane & 15, q = lane >> 4;

    f32x4 acc[4][4] = {};

    for (int k0 = 0; k0 < DIN; k0 += 64) {
        __syncthreads();
        #pragma unroll
        for (int j = 0; j < 4; j++) {
            int gidx = (w * 4 + j) * 64 + lane;
            int row = gidx >> 3, slot = gidx & 7;
            int src = slot ^ (row & 7);
            const unsigned short* ga = xb + (size_t)(m0 + row) * DIN + k0 + src * 8;
            const unsigned short* gb = Wt + (size_t)(n0 + row) * DIN + k0 + src * 8;
            async16(ga, As + (w * 4 + j) * 512);
            async16(gb, Bs + (w * 4 + j) * 512);
        }
        __syncthreads();
        #pragma unroll
        for (int ks = 0; ks < 2; ks++) {
            bf16x8 af[4], bfr[4];
            #pragma unroll
            for (int i = 0; i < 4; i++) {
                int row = wm + i * 16 + lrow;
                int phys = (ks * 4 + q) ^ (row & 7);
                af[i] = *reinterpret_cast<const bf16x8*>(As + row * 64 + phys * 8);
            }
            #pragma unroll
            for (int j = 0; j < 4; j++) {
                int row = wn + j * 16 + lrow;
                int phys = (ks * 4 + q) ^ (row & 7);
                bfr[j] = *reinterpret_cast<const bf16x8*>(Bs + row * 64 + phys * 8);
            }
            #pragma unroll
            for (int i = 0; i < 4; i++)
                #pragma unroll
                for (int j = 0; j < 4; j++)
                    acc[i][j] = __builtin_amdgcn_mfma_f32_16x16x32_bf16(af[i], bfr[j], acc[i][j], 0, 0, 0);
        }
    }
    #pragma unroll
    for (int i = 0; i < 4; i++)
        #pragma unroll
        for (int j = 0; j < 4; j++) {
            int col = n0 + wn + j * 16 + lrow;
            int rbase = m0 + wm + i * 16 + q * 4;
            #pragma unroll
            for (int r = 0; r < 4; r++)
                Zb[(size_t)(rbase + r) * NTOT + col] = f2bf(acc[i][j][r]);
        }
}

// ------- 2-row attn block: stage ; {LN || Gram} ; repack+stats ; MFMA tanh ; y -------
// 3 barriers; LN (global-only, waves 0-1) runs concurrently with Gram-MFMA
// (LDS-only, waves 2-3); fragments go to separate buffers (no in-place hazard).
__global__ __launch_bounds__(256, 8) void attn_kernel(const unsigned short* __restrict__ Zb,
                                                      const float* __restrict__ bh,
                                                      const float* __restrict__ lns,
                                                      const float* __restrict__ lnb,
                                                      float* __restrict__ h_out,
                                                      float* __restrict__ y_out) {
    __shared__ __align__(16) unsigned short z1a[RPB * RREG + 7 * SH]; // raw z1 (+MFMA overrun pad)
    __shared__ __align__(16) unsigned short z1cb[RPB][DH * 8];        // centered [d][h]
    __shared__ __align__(16) unsigned short z2b[RPB][1024];           // raw z2 [h][g]
    __shared__ __align__(16) unsigned short z2A[RPB][1024];           // scaled [g][h]
    __shared__ __align__(16) float hsr[RPB][DH];
    __shared__ float GLr[RPB][9][9];
    __shared__ float redH[RPB];
    __shared__ __align__(16) unsigned short zpad[8];
    const int b0 = blockIdx.x * RPB;
    const int t = threadIdx.x;
    const int wv = t >> 6, lane = t & 63;
    const int lrow = lane & 15, q = lane >> 4;

    // ---- stage: z1 (1 uint4/thread/row), z2 (1 uint4/thread), ones, zpad ----
    #pragma unroll
    for (int r = 0; r < RPB; r++) {
        uint4 v = *(const uint4*)(Zb + (size_t)(b0 + r) * NTOT + 256 + t * 8);
        *(uint4*)(z1a + r * RREG + (t >> 5) * SH + (t & 31) * 8) = v;
        z1a[r * RREG + 8 * SH + t] = 0x3F80;   // bf16 1.0 ones row
    }
    {
        int r = t >> 7, c = t & 127;
        uint4 v = *(const uint4*)(Zb + (size_t)(b0 + r) * NTOT + 2304 + c * 8);
        *(uint4*)(&z2b[r][c * 8]) = v;
    }
    if (t < 8) zpad[t] = 0;
    __syncthreads();   // (#1) staging visible

    if (wv < 2) {
        // ---- LN row wv: global reads only, full-wave shuffle ----
        int r = wv, d0 = lane * 4;
        const unsigned short* Zr = Zb + (size_t)(b0 + r) * NTOT;
        ushort4 hu = *(const ushort4*)(Zr + d0);
        float4 bv = *(const float4*)(bh + d0);
        float vv[4];
        vv[0] = fmaxf(bf2f(hu.x) + bv.x, 0.f);
        vv[1] = fmaxf(bf2f(hu.y) + bv.y, 0.f);
        vv[2] = fmaxf(bf2f(hu.z) + bv.z, 0.f);
        vv[3] = fmaxf(bf2f(hu.w) + bv.w, 0.f);
        float s = vv[0] + vv[1] + vv[2] + vv[3];
        float sq = vv[0] * vv[0] + vv[1] * vv[1] + vv[2] * vv[2] + vv[3] * vv[3];
        #pragma unroll
        for (int m = 32; m >= 1; m >>= 1) {
            s  += __shfl_xor(s,  m, 64);
            sq += __shfl_xor(sq, m, 64);
        }
        float mu  = s * (1.0f / 256.0f);
        float var = sq * (1.0f / 256.0f) - mu * mu;
        float rs = rsqrtf(var + 1e-6f);
        float4 lv = *(const float4*)(lns + d0);
        float4 ov = *(const float4*)(lnb + d0);
        float hv0 = (vv[0] - mu) * rs * lv.x + ov.x;
        float hv1 = (vv[1] - mu) * rs * lv.y + ov.y;
        float hv2 = (vv[2] - mu) * rs * lv.z + ov.z;
        float hv3 = (vv[3] - mu) * rs * lv.w + ov.w;
        *(float4*)(&hsr[r][d0]) = float4{hv0, hv1, hv2, hv3};
        *(float4*)(h_out + (size_t)(b0 + r) * DH + d0) = float4{hv0, hv1, hv2, hv3};
        float hp = hv0 + hv1 + hv2 + hv3;
        #pragma unroll
        for (int m = 32; m >= 1; m >>= 1) hp += __shfl_xor(hp, m, 64);
        if (lane == 0) redH[r] = hp;
    } else {
        // ---- Gram row wv-2 via MFMA: LDS reads only ----
        int r = wv - 2;
        f32x4 g = {};
        #pragma unroll
        for (int ks = 0; ks < 8; ks++) {
            bf16x8 fr = *reinterpret_cast<const bf16x8*>(z1a + r * RREG + lrow * SH + ks * 32 + q * 8);
            g = __builtin_amdgcn_mfma_f32_16x16x32_bf16(fr, fr, g, 0, 0, 0);
        }
        #pragma unroll
        for (int i = 0; i < 4; i++) {
            int crow = q * 4 + i;
            if (crow < 9 && lrow < 9) GLr[r][crow][lrow] = g[i];
        }
    }
    __syncthreads();   // (#2) hsr/redH + GLr visible

    // ---- repack + stats (all threads; row sr = t>>7) ----
    const int sr = t >> 7, sg = t & 127;
    {
        float mh[NH];
        #pragma unroll
        for (int h = 0; h < NH; h++) mh[h] = GLr[sr][h][8] * (1.0f / 256.0f);
        #pragma unroll
        for (int it = 0; it < 2; it++) {
            int d = sg + it * 128;
            uint32_t pk[4];
            #pragma unroll
            for (int h2 = 0; h2 < 4; h2++) {
                float c0 = bf2f(z1a[sr * RREG + (2 * h2) * SH + d])     - mh[2 * h2];
                float c1 = bf2f(z1a[sr * RREG + (2 * h2 + 1) * SH + d]) - mh[2 * h2 + 1];
                pk[h2] = (uint32_t)f2bf(c0) | ((uint32_t)f2bf(c1) << 16);
            }
            *(uint4*)(&z1cb[sr][d * 8]) = uint4{pk[0], pk[1], pk[2], pk[3]};
        }
    }
    {
        float z2g[NH];
        #pragma unroll
        for (int h = 0; h < NH; h++) z2g[h] = bf2f(z2b[sr][h * 128 + sg]);
        float mug = 0.f, qg = 0.f;
        #pragma unroll
        for (int h = 0; h < NH; h++) {
            mug += z2g[h] * GLr[sr][h][8];
            float inn = 0.f;
            #pragma unroll
            for (int h2 = 0; h2 < NH; h2++) inn += z2g[h2] * GLr[sr][h][h2];
            qg += z2g[h] * inn;
        }
        mug *= (1.0f / 256.0f);
        qg  *= (1.0f / 256.0f);
        float vg = fmaxf(qg - mug * mug, 0.0f);
        float A = 2.0f * 1.4426950408889634f / (sqrtf(vg) + 1e-6f);
        uint32_t pk[4];
        #pragma unroll
        for (int h2 = 0; h2 < 4; h2++)
            pk[h2] = (uint32_t)f2bf(z2g[2 * h2] * A) | ((uint32_t)f2bf(z2g[2 * h2 + 1] * A) << 16);
        *(uint4*)(&z2A[sr][sg * 8]) = uint4{pk[0], pk[1], pk[2], pk[3]};
    }
    __syncthreads();   // (#3) fragments ready

    // ---- main: wave wv -> row = wv>>1, g-tiles (wv&1)*4 .. +3 (R10-proven) ----
    const int row = wv >> 1, gtb = (wv & 1) * 4;
    const unsigned short* bp = (q == 0) ? (&z1cb[row][lrow * 8]) : zpad;
    const int binc = (q == 0) ? 128 : 0;
    bf16x8 af[4];
    #pragma unroll
    for (int gt = 0; gt < 4; gt++) {
        const unsigned short* pa = (q == 0) ? (&z2A[row][((gtb + gt) * 16 + lrow) * 8]) : zpad;
        af[gt] = *reinterpret_cast<const bf16x8*>(pa);
    }
    f32x4 czero = {};
    float yn[4][4] = {};
    #pragma unroll 4
    for (int dt = 0; dt < 16; dt++) {
        bf16x8 bfr = *reinterpret_cast<const bf16x8*>(bp + dt * binc);
        float hv = hsr[row][dt * 16 + lrow];
        #pragma unroll
        for (int gt = 0; gt < 4; gt++) {
            f32x4 c = __builtin_amdgcn_mfma_f32_16x16x32_bf16(af[gt], bfr, czero, 0, 0, 0);
            #pragma unroll
            for (int r4 = 0; r4 < 4; r4++) {
                float e = __builtin_amdgcn_exp2f(c[r4]);
                yn[gt][r4] = fmaf(hv, __builtin_amdgcn_rcpf(e + 1.0f), yn[gt][r4]);
            }
        }
    }
    #pragma unroll
    for (int m = 1; m <= 8; m <<= 1)
        #pragma unroll
        for (int gt = 0; gt < 4; gt++)
            #pragma unroll
            for (int r4 = 0; r4 < 4; r4++)
                yn[gt][r4] += __shfl_xor(yn[gt][r4], m, 64);
    if (lrow == 0) {
        float Hs = redH[row];
        #pragma unroll
        for (int gt = 0; gt < 4; gt++)
            #pragma unroll
            for (int r4 = 0; r4 < 4; r4++)
                y_out[(size_t)(b0 + row) * DG + (gtb + gt) * 16 + q * 4 + r4] = Hs - 2.0f * yn[gt][r4];
    }
}

extern "C" void kernel_launch(void* const* d_in, const int* in_sizes, int n_in,
                              void* d_out, int out_size, void* d_ws, size_t ws_size,
                              hipStream_t stream) {
    const float* x   = (const float*)d_in[0];
    const float* Wh  = (const float*)d_in[1];
    const float* bh  = (const float*)d_in[2];
    const float* Wz1 = (const float*)d_in[3];
    const float* Wz2 = (const float*)d_in[4];
    const float* lns = (const float*)d_in[5];
    const float* lnb = (const float*)d_in[6];
    float* h_out = (float*)d_out;
    float* y_out = h_out + (size_t)BATCH * DH;

    char* ws = (char*)d_ws;
    unsigned short* Zb = (unsigned short*)ws;               // 27,262,976 B
    unsigned short* xb = (unsigned short*)(ws + 27262976);  //  4,194,304 B
    unsigned short* Wt = (unsigned short*)(ws + 31457280);  //  3,407,872 B (~34.9 MB)

    prep_kernel<<<3712, 256, 0, stream>>>(x, Wh, Wz1, Wz2, xb, Wt);
    gemm_kernel<<<dim3(NTOT / 128, BATCH / 128), 256, 0, stream>>>(xb, Wt, Zb);
    attn_kernel<<<BATCH / RPB, 256, 0, stream>>>(Zb, bh, lns, lnb, h_out, y_out);
}

// Round 12
// 140.821 us; speedup vs baseline: 1.0338x; 1.0055x over previous
//
#include <hip/hip_runtime.h>
#include <hip/hip_bf16.h>
#include <cstdint>

#define BATCH 4096
#define DIN   512
#define DH    256
#define DG    128
#define NH    8
#define NTOT  3328
#define RPB   2          // rows per attn block
#define SH    264        // raw-z1 row stride in shorts (528B rows -> 2-way banks, free)
#define RREG  (9 * SH)   // per-row raw z1 region: 8 heads + ones row

typedef __bf16 bf16x8 __attribute__((ext_vector_type(8)));
typedef float  f32x4  __attribute__((ext_vector_type(4)));

__device__ __forceinline__ unsigned short f2bf(float f) {
    union { float f; uint32_t u; } v; v.f = f;
    uint32_t u = v.u;
    u += 0x7fffu + ((u >> 16) & 1u);
    return (unsigned short)(u >> 16);
}
__device__ __forceinline__ float bf2f(unsigned short s) {
    union { uint32_t u; float f; } v; v.u = ((uint32_t)s) << 16;
    return v.f;
}

__device__ __forceinline__ void async16(const unsigned short* g, unsigned short* l) {
    __builtin_amdgcn_global_load_lds(
        (const __attribute__((address_space(1))) unsigned int*)(uintptr_t)g,
        (__attribute__((address_space(3))) unsigned int*)(uintptr_t)l,
        16, 0, 0);
}

// ---------------- merged prep: cvt_x + transpose/concat weights (R5-proven, FROZEN) ----------------
__global__ __launch_bounds__(256) void prep_kernel(const float* __restrict__ x,
                                                   const float* __restrict__ Wh,
                                                   const float* __restrict__ Wz1,
                                                   const float* __restrict__ Wz2,
                                                   unsigned short* __restrict__ xb,
                                                   unsigned short* __restrict__ Wt) {
    __shared__ float tile[32][33];
    int bid = blockIdx.x;
    int t = threadIdx.x;
    if (bid < 2048) {
        int i = (bid * 256 + t) * 4;
        float4 v = *(const float4*)(x + i);
        ushort4 o;
        o.x = f2bf(v.x); o.y = f2bf(v.y); o.z = f2bf(v.z); o.w = f2bf(v.w);
        *(ushort4*)(xb + i) = o;
        return;
    }
    int b2 = bid - 2048;
    int n0 = (b2 % 104) * 32;
    int k0 = (b2 / 104) * 32;
    const float* W; int ldn, nl;
    if (n0 < 256)       { W = Wh;  ldn = 256;  nl = n0; }
    else if (n0 < 2304) { W = Wz1; ldn = 2048; nl = n0 - 256; }
    else                { W = Wz2; ldn = 1024; nl = n0 - 2304; }
    int tx = t & 31, ty = t >> 5;
    #pragma unroll
    for (int i = 0; i < 4; i++) {
        int kk = ty + i * 8;
        tile[kk][tx] = W[(size_t)(k0 + kk) * ldn + nl + tx];
    }
    __syncthreads();
    #pragma unroll
    for (int i = 0; i < 4; i++) {
        int nn = ty + i * 8;
        Wt[(size_t)(n0 + nn) * 512 + k0 + tx] = f2bf(tile[tx][nn]);
    }
}

// ------------- fused GEMM: Zb[4096][3328](bf16) = xb @ Wt^T -------------
// R12: BK reverted 64->32 (m97-proven shape; 16KB LDS doubles resident
// blocks to hide the pre-barrier vmcnt drain). 4-chunk XOR swizzle.
__global__ __launch_bounds__(256) void gemm_kernel(const unsigned short* __restrict__ xb,
                                                   const unsigned short* __restrict__ Wt,
                                                   unsigned short* __restrict__ Zb) {
    __shared__ unsigned short As[128 * 32];  // 8KB
    __shared__ unsigned short Bs[128 * 32];  // 8KB
    const int m0 = blockIdx.y * 128;
    const int n0 = blockIdx.x * 128;
    const int t = threadIdx.x;
    const int w = t >> 6, lane = t & 63;
    const int wm = (w >> 1) * 64, wn = (w & 1) * 64;
    const int lrow = lane & 15, q = lane >> 4;
    const int swz = q ^ (lrow & 3);          // physical chunk for logical chunk q

    f32x4 acc[4][4] = {};

    for (int k0 = 0; k0 < DIN; k0 += 32) {
        __syncthreads();
        #pragma unroll
        for (int j = 0; j < 2; j++) {
            int gidx = (w * 2 + j) * 64 + lane;     // chunk id 0..511 (16B chunks)
            int row = gidx >> 2, slot = gidx & 3;   // 64B row = 4 chunks
            int src = slot ^ (row & 3);
            const unsigned short* ga = xb + (size_t)(m0 + row) * DIN + k0 + src * 8;
            const unsigned short* gb = Wt + (size_t)(n0 + row) * DIN + k0 + src * 8;
            async16(ga, As + (w * 2 + j) * 512);
            async16(gb, Bs + (w * 2 + j) * 512);
        }
        __syncthreads();   // drains vmcnt -> staged data visible
        bf16x8 af[4], bfr[4];
        #pragma unroll
        for (int i = 0; i < 4; i++) {
            int row = wm + i * 16 + lrow;
            af[i] = *reinterpret_cast<const bf16x8*>(As + row * 32 + ((q ^ (row & 3)) * 8));
        }
        #pragma unroll
        for (int j = 0; j < 4; j++) {
            int row = wn + j * 16 + lrow;
            bfr[j] = *reinterpret_cast<const bf16x8*>(Bs + row * 32 + ((q ^ (row & 3)) * 8));
        }
        #pragma unroll
        for (int i = 0; i < 4; i++)
            #pragma unroll
            for (int j = 0; j < 4; j++)
                acc[i][j] = __builtin_amdgcn_mfma_f32_16x16x32_bf16(af[i], bfr[j], acc[i][j], 0, 0, 0);
    }
    #pragma unroll
    for (int i = 0; i < 4; i++)
        #pragma unroll
        for (int j = 0; j < 4; j++) {
            int col = n0 + wn + j * 16 + lrow;
            int rbase = m0 + wm + i * 16 + q * 4;
            #pragma unroll
            for (int r = 0; r < 4; r++)
                Zb[(size_t)(rbase + r) * NTOT + col] = f2bf(acc[i][j][r]);
        }
}

// ------- 2-row attn block: stage ; {LN || Gram} ; repack+stats ; MFMA tanh ; y (R11-proven, FROZEN) -------
__global__ __launch_bounds__(256, 8) void attn_kernel(const unsigned short* __restrict__ Zb,
                                                      const float* __restrict__ bh,
                                                      const float* __restrict__ lns,
                                                      const float* __restrict__ lnb,
                                                      float* __restrict__ h_out,
                                                      float* __restrict__ y_out) {
    __shared__ __align__(16) unsigned short z1a[RPB * RREG + 7 * SH]; // raw z1 (+MFMA overrun pad)
    __shared__ __align__(16) unsigned short z1cb[RPB][DH * 8];        // centered [d][h]
    __shared__ __align__(16) unsigned short z2b[RPB][1024];           // raw z2 [h][g]
    __shared__ __align__(16) unsigned short z2A[RPB][1024];           // scaled [g][h]
    __shared__ __align__(16) float hsr[RPB][DH];
    __shared__ float GLr[RPB][9][9];
    __shared__ float redH[RPB];
    __shared__ __align__(16) unsigned short zpad[8];
    const int b0 = blockIdx.x * RPB;
    const int t = threadIdx.x;
    const int wv = t >> 6, lane = t & 63;
    const int lrow = lane & 15, q = lane >> 4;

    // ---- stage ----
    #pragma unroll
    for (int r = 0; r < RPB; r++) {
        uint4 v = *(const uint4*)(Zb + (size_t)(b0 + r) * NTOT + 256 + t * 8);
        *(uint4*)(z1a + r * RREG + (t >> 5) * SH + (t & 31) * 8) = v;
        z1a[r * RREG + 8 * SH + t] = 0x3F80;   // bf16 1.0 ones row
    }
    {
        int r = t >> 7, c = t & 127;
        uint4 v = *(const uint4*)(Zb + (size_t)(b0 + r) * NTOT + 2304 + c * 8);
        *(uint4*)(&z2b[r][c * 8]) = v;
    }
    if (t < 8) zpad[t] = 0;
    __syncthreads();   // (#1) staging visible

    if (wv < 2) {
        // ---- LN row wv: global reads only, full-wave shuffle ----
        int r = wv, d0 = lane * 4;
        const unsigned short* Zr = Zb + (size_t)(b0 + r) * NTOT;
        ushort4 hu = *(const ushort4*)(Zr + d0);
        float4 bv = *(const float4*)(bh + d0);
        float vv[4];
        vv[0] = fmaxf(bf2f(hu.x) + bv.x, 0.f);
        vv[1] = fmaxf(bf2f(hu.y) + bv.y, 0.f);
        vv[2] = fmaxf(bf2f(hu.z) + bv.z, 0.f);
        vv[3] = fmaxf(bf2f(hu.w) + bv.w, 0.f);
        float s = vv[0] + vv[1] + vv[2] + vv[3];
        float sq = vv[0] * vv[0] + vv[1] * vv[1] + vv[2] * vv[2] + vv[3] * vv[3];
        #pragma unroll
        for (int m = 32; m >= 1; m >>= 1) {
            s  += __shfl_xor(s,  m, 64);
            sq += __shfl_xor(sq, m, 64);
        }
        float mu  = s * (1.0f / 256.0f);
        float var = sq * (1.0f / 256.0f) - mu * mu;
        float rs = rsqrtf(var + 1e-6f);
        float4 lv = *(const float4*)(lns + d0);
        float4 ov = *(const float4*)(lnb + d0);
        float hv0 = (vv[0] - mu) * rs * lv.x + ov.x;
        float hv1 = (vv[1] - mu) * rs * lv.y + ov.y;
        float hv2 = (vv[2] - mu) * rs * lv.z + ov.z;
        float hv3 = (vv[3] - mu) * rs * lv.w + ov.w;
        *(float4*)(&hsr[r][d0]) = float4{hv0, hv1, hv2, hv3};
        *(float4*)(h_out + (size_t)(b0 + r) * DH + d0) = float4{hv0, hv1, hv2, hv3};
        float hp = hv0 + hv1 + hv2 + hv3;
        #pragma unroll
        for (int m = 32; m >= 1; m >>= 1) hp += __shfl_xor(hp, m, 64);
        if (lane == 0) redH[r] = hp;
    } else {
        // ---- Gram row wv-2 via MFMA: LDS reads only ----
        int r = wv - 2;
        f32x4 g = {};
        #pragma unroll
        for (int ks = 0; ks < 8; ks++) {
            bf16x8 fr = *reinterpret_cast<const bf16x8*>(z1a + r * RREG + lrow * SH + ks * 32 + q * 8);
            g = __builtin_amdgcn_mfma_f32_16x16x32_bf16(fr, fr, g, 0, 0, 0);
        }
        #pragma unroll
        for (int i = 0; i < 4; i++) {
            int crow = q * 4 + i;
            if (crow < 9 && lrow < 9) GLr[r][crow][lrow] = g[i];
        }
    }
    __syncthreads();   // (#2) hsr/redH + GLr visible

    // ---- repack + stats (all threads; row sr = t>>7) ----
    const int sr = t >> 7, sg = t & 127;
    {
        float mh[NH];
        #pragma unroll
        for (int h = 0; h < NH; h++) mh[h] = GLr[sr][h][8] * (1.0f / 256.0f);
        #pragma unroll
        for (int it = 0; it < 2; it++) {
            int d = sg + it * 128;
            uint32_t pk[4];
            #pragma unroll
            for (int h2 = 0; h2 < 4; h2++) {
                float c0 = bf2f(z1a[sr * RREG + (2 * h2) * SH + d])     - mh[2 * h2];
                float c1 = bf2f(z1a[sr * RREG + (2 * h2 + 1) * SH + d]) - mh[2 * h2 + 1];
                pk[h2] = (uint32_t)f2bf(c0) | ((uint32_t)f2bf(c1) << 16);
            }
            *(uint4*)(&z1cb[sr][d * 8]) = uint4{pk[0], pk[1], pk[2], pk[3]};
        }
    }
    {
        float z2g[NH];
        #pragma unroll
        for (int h = 0; h < NH; h++) z2g[h] = bf2f(z2b[sr][h * 128 + sg]);
        float mug = 0.f, qg = 0.f;
        #pragma unroll
        for (int h = 0; h < NH; h++) {
            mug += z2g[h] * GLr[sr][h][8];
            float inn = 0.f;
            #pragma unroll
            for (int h2 = 0; h2 < NH; h2++) inn += z2g[h2] * GLr[sr][h][h2];
            qg += z2g[h] * inn;
        }
        mug *= (1.0f / 256.0f);
        qg  *= (1.0f / 256.0f);
        float vg = fmaxf(qg - mug * mug, 0.0f);
        float A = 2.0f * 1.4426950408889634f / (sqrtf(vg) + 1e-6f);
        uint32_t pk[4];
        #pragma unroll
        for (int h2 = 0; h2 < 4; h2++)
            pk[h2] = (uint32_t)f2bf(z2g[2 * h2] * A) | ((uint32_t)f2bf(z2g[2 * h2 + 1] * A) << 16);
        *(uint4*)(&z2A[sr][sg * 8]) = uint4{pk[0], pk[1], pk[2], pk[3]};
    }
    __syncthreads();   // (#3) fragments ready

    // ---- main: wave wv -> row = wv>>1, g-tiles (wv&1)*4 .. +3 ----
    const int row = wv >> 1, gtb = (wv & 1) * 4;
    const unsigned short* bp = (q == 0) ? (&z1cb[row][lrow * 8]) : zpad;
    const int binc = (q == 0) ? 128 : 0;
    bf16x8 af[4];
    #pragma unroll
    for (int gt = 0; gt < 4; gt++) {
        const unsigned short* pa = (q == 0) ? (&z2A[row][((gtb + gt) * 16 + lrow) * 8]) : zpad;
        af[gt] = *reinterpret_cast<const bf16x8*>(pa);
    }
    f32x4 czero = {};
    float yn[4][4] = {};
    #pragma unroll 4
    for (int dt = 0; dt < 16; dt++) {
        bf16x8 bfr = *reinterpret_cast<const bf16x8*>(bp + dt * binc);
        float hv = hsr[row][dt * 16 + lrow];
        #pragma unroll
        for (int gt = 0; gt < 4; gt++) {
            f32x4 c = __builtin_amdgcn_mfma_f32_16x16x32_bf16(af[gt], bfr, czero, 0, 0, 0);
            #pragma unroll
            for (int r4 = 0; r4 < 4; r4++) {
                float e = __builtin_amdgcn_exp2f(c[r4]);
                yn[gt][r4] = fmaf(hv, __builtin_amdgcn_rcpf(e + 1.0f), yn[gt][r4]);
            }
        }
    }
    #pragma unroll
    for (int m = 1; m <= 8; m <<= 1)
        #pragma unroll
        for (int gt = 0; gt < 4; gt++)
            #pragma unroll
            for (int r4 = 0; r4 < 4; r4++)
                yn[gt][r4] += __shfl_xor(yn[gt][r4], m, 64);
    if (lrow == 0) {
        float Hs = redH[row];
        #pragma unroll
        for (int gt = 0; gt < 4; gt++)
            #pragma unroll
            for (int r4 = 0; r4 < 4; r4++)
                y_out[(size_t)(b0 + row) * DG + (gtb + gt) * 16 + q * 4 + r4] = Hs - 2.0f * yn[gt][r4];
    }
}

extern "C" void kernel_launch(void* const* d_in, const int* in_sizes, int n_in,
                              void* d_out, int out_size, void* d_ws, size_t ws_size,
                              hipStream_t stream) {
    const float* x   = (const float*)d_in[0];
    const float* Wh  = (const float*)d_in[1];
    const float* bh  = (const float*)d_in[2];
    const float* Wz1 = (const float*)d_in[3];
    const float* Wz2 = (const float*)d_in[4];
    const float* lns = (const float*)d_in[5];
    const float* lnb = (const float*)d_in[6];
    float* h_out = (float*)d_out;
    float* y_out = h_out + (size_t)BATCH * DH;

    char* ws = (char*)d_ws;
    unsigned short* Zb = (unsigned short*)ws;               // 27,262,976 B
    unsigned short* xb = (unsigned short*)(ws + 27262976);  //  4,194,304 B
    unsigned short* Wt = (unsigned short*)(ws + 31457280);  //  3,407,872 B (~34.9 MB)

    prep_kernel<<<3712, 256, 0, stream>>>(x, Wh, Wz1, Wz2, xb, Wt);
    gemm_kernel<<<dim3(NTOT / 128, BATCH / 128), 256, 0, stream>>>(xb, Wt, Zb);
    attn_kernel<<<BATCH / RPB, 256, 0, stream>>>(Zb, bh, lns, lnb, h_out, y_out);
}